// Round 8
// baseline (309.867 us; speedup 1.0000x reference)
//
#include <hip/hip_runtime.h>
#include <hip/hip_cooperative_groups.h>
#include <stdint.h>

namespace cg = cooperative_groups;

// B=4, Q=4096, V=4096, H=128, fp32 in/out
#define NBATCH 4
#define NQ 4096
#define NV 4096
#define HD 128

// SCALE * log2(e): scores scaled into exp2 domain
#define SCL2E ((float)(11.31370849898476 * 1.4426950408889634))

// keep  <=>  bits < 0.9f in fixed point (0.9f = 7549747 * 2^-23)
#define KEEP_THRESH 3865470464u
#define EPS_SKIP 1e-6f

// --- ws layout (converted K/V) ---
// per (batch,tile) record: [khi 8192 ush][klo 8192 ush][vt 8192 ush] = 48 KB
// chunk = 8 ushorts = 16B.  XOR-swizzled chunk positions (2-way bank = free):
#define CHK_K(v,c) ((((v) * 16) + (((c) ^ (v)) & 15)) * 8)   // v 0..63, c 0..15
#define CHK_V(h,c) ((((h) * 8)  + (((c) ^ (h)) & 7))  * 8)   // h 0..127, c 0..7
#define TILE_USH 24576
#define WS_NEEDED ((size_t)NBATCH * 64 * TILE_USH * 2)       // 12,582,912 B

#define PSTR2 40   // pls row stride (ushorts): 16 rows x 32 cols + pad
#define VLSTR 142  // phase-1 LDS v-tile stride (ushorts)

// --- fallback path constants (round-3 kernel, verified passing) ---
#define KSTR 144
#define VSTR 76
#define PSTR 72

typedef __attribute__((ext_vector_type(8))) short short8;   // 8 bf16 (MFMA A/B frag)
typedef __attribute__((ext_vector_type(4))) float floatx4;  // MFMA C/D frag
typedef unsigned int uint;
typedef unsigned short ushort;
typedef __attribute__((address_space(3))) uint lds_u32;
typedef __attribute__((address_space(1))) const uint glb_u32;

__device__ __forceinline__ ushort bf16rne(float f) {
    uint u = __float_as_uint(f);
    u = (u + 0x7fffu + ((u >> 16) & 1u)) >> 16;
    return (ushort)u;
}
__device__ __forceinline__ float bf2f(ushort h) {
    return __uint_as_float(((uint)h) << 16);
}

// ---- DPP 16-lane reductions (VALU-only, no DS pipe) ----
template <int CTRL>
__device__ __forceinline__ float dppmov(float x) {
    return __int_as_float(__builtin_amdgcn_update_dpp(
        0, __float_as_int(x), CTRL, 0xF, 0xF, true));
}
__device__ __forceinline__ float row_max16(float x) {
    x = fmaxf(x, dppmov<0xB1>(x));    // quad_perm xor1
    x = fmaxf(x, dppmov<0x4E>(x));    // quad_perm xor2
    x = fmaxf(x, dppmov<0x141>(x));   // row_half_mirror
    x = fmaxf(x, dppmov<0x140>(x));   // row_mirror
    return x;
}
__device__ __forceinline__ float row_sum16(float x) {
    x += dppmov<0xB1>(x);
    x += dppmov<0x4E>(x);
    x += dppmov<0x141>(x);
    x += dppmov<0x140>(x);
    return x;
}

__device__ __forceinline__ uint rotl(uint x, int r) { return (x << r) | (x >> (32 - r)); }

// JAX threefry2x32 partitionable path, key=(0,42): bits = y0 ^ y1 of hash of 64-bit counter j
__device__ __forceinline__ uint threefry_bits(uint j) {
    uint x0 = 0u;   // counter hi word (all j < 2^32)
    uint x1 = j;
    const uint k0 = 0u, k1 = 42u, k2 = 0u ^ 42u ^ 0x1BD11BDAu;
    x0 += k0; x1 += k1;
#define TFR4(a,b,c,d) \
    x0 += x1; x1 = rotl(x1, a); x1 ^= x0; \
    x0 += x1; x1 = rotl(x1, b); x1 ^= x0; \
    x0 += x1; x1 = rotl(x1, c); x1 ^= x0; \
    x0 += x1; x1 = rotl(x1, d); x1 ^= x0;
    TFR4(13, 15, 26, 6)
    x0 += k1; x1 += k2 + 1u;
    TFR4(17, 29, 16, 24)
    x0 += k2; x1 += k0 + 2u;
    TFR4(13, 15, 26, 6)
    x0 += k0; x1 += k1 + 3u;
    TFR4(17, 29, 16, 24)
    x0 += k1; x1 += k2 + 4u;
    TFR4(13, 15, 26, 6)
    x0 += k2; x1 += k0 + 5u;
#undef TFR4
    return x0 ^ x1;
}

// ============================ phase-1 body (K/V convert) ============================
// unit in [0,512): rec = unit>>1 (batch,tile), half 0 = K convert, half 1 = V transpose.
// vls: >= 64*VLSTR ushorts of LDS scratch (aliased into kbuf in the fused kernel).
__device__ __forceinline__ void prepass_body(const float* __restrict__ Kg,
                                             const float* __restrict__ Vg,
                                             ushort* __restrict__ W,
                                             int unit, int tid, ushort* vls) {
    const int rec  = unit >> 1;
    const int half = unit & 1;
    const int bb = rec >> 6;
    const int t  = rec & 63;
    const int v0 = t * 64;
    const size_t kvbase = (size_t)bb * NV * HD;
    ushort* dst = W + ((size_t)bb * 64 + t) * TILE_USH;

    if (half == 0) {
        // K: 1024 chunks (64 rows x 16 chunk-cols), hi/lo split, coalesced both sides
        ushort* dkh = dst;
        ushort* dkl = dst + 8192;
#pragma unroll
        for (int i = 0; i < 4; ++i) {
            int lc = i * 256 + tid;
            int v = lc >> 4, c = lc & 15;
            const float* src = Kg + kvbase + (size_t)(v0 + v) * HD + c * 8;
            float x[8];
            *(float4*)&x[0] = *(const float4*)src;
            *(float4*)&x[4] = *(const float4*)(src + 4);
            uint H[4], L[4];
#pragma unroll
            for (int k = 0; k < 4; ++k) {
                ushort h0 = bf16rne(x[2 * k]),     h1 = bf16rne(x[2 * k + 1]);
                ushort l0 = bf16rne(x[2 * k] - bf2f(h0));
                ushort l1 = bf16rne(x[2 * k + 1] - bf2f(h1));
                H[k] = (uint)h0 | ((uint)h1 << 16);
                L[k] = (uint)l0 | ((uint)l1 << 16);
            }
            int pos = CHK_K(v, c);
            *(uint4*)&dkh[pos] = *(uint4*)H;
            *(uint4*)&dkl[pos] = *(uint4*)L;
        }
    } else {
        // V phase A: coalesced float4 row reads -> bf16 LDS tile [v][h]
        ushort* dvt = dst + 16384;
#pragma unroll
        for (int i = 0; i < 8; ++i) {
            int idx = i * 256 + tid;
            int v = idx >> 5, hq = idx & 31;
            float4 a = *(const float4*)(Vg + kvbase + (size_t)(v0 + v) * HD + hq * 4);
            uint w0 = (uint)bf16rne(a.x) | ((uint)bf16rne(a.y) << 16);
            uint w1 = (uint)bf16rne(a.z) | ((uint)bf16rne(a.w) << 16);
            *(uint*)&vls[v * VLSTR + hq * 4]     = w0;
            *(uint*)&vls[v * VLSTR + hq * 4 + 2] = w1;
        }
        __syncthreads();
        // V phase B: transposed reads, chunk writes in OUTPUT order (coalesced)
#pragma unroll
        for (int i = 0; i < 4; ++i) {
            int oc = i * 256 + tid;
            int h = oc >> 3, swz = oc & 7;
            int c2 = (swz ^ h) & 7;
            uint Wd[4];
#pragma unroll
            for (int m = 0; m < 8; m += 2) {
                ushort a  = vls[(c2 * 8 + m) * VLSTR + h];
                ushort b2 = vls[(c2 * 8 + m + 1) * VLSTR + h];
                Wd[m >> 1] = (uint)a | ((uint)b2 << 16);
            }
            *(uint4*)&dvt[oc * 8] = *(uint4*)Wd;
        }
    }
}

// ============================ phase-2 body (attention) ============================
// blockid in [0,512): 32 q-rows. 4 waves: rg = row-group (16 rows), cw = col half.
// K single-buffered (2 barriers/tile), V double-buffered, split-softmax pair merge.
// Fragment layouts (gfx950 mfma_f32_16x16x32_bf16, m89/m120-verified):
//   A: lane holds A[m = lane&15][k = (lane>>4)*8 + j]
//   B: lane holds B[k = (lane>>4)*8 + j][n = lane&15]
//   C/D: lane holds D[row = (lane>>4)*4 + reg][col = lane&15]
__device__ __forceinline__ void fa_body(const float* __restrict__ Qg,
                                        const ushort* __restrict__ Wk,
                                        float* __restrict__ Og,
                                        int blockid, int tid,
                                        ushort* kbuf, ushort (*vbuf)[8192],
                                        ushort (*pls)[16 * PSTR2], float (*mrow)[32]) {
    const int wave = tid >> 6;
    const int lane = tid & 63;
    const int r    = lane & 15;
    const int qd   = lane >> 4;
    const int rg   = wave >> 1;
    const int cw   = wave & 1;
    const int blockRow0 = blockid * 32;
    const int b = blockRow0 >> 12;
    const int waveRow0 = blockRow0 + rg * 16;
    const ushort* kvw = Wk + (size_t)b * 64 * TILE_USH;

    // Q -> A-fragments (hi/lo bf16 split), registers
    short8 qfh[4], qfl[4];
    {
        const float* qp = Qg + (size_t)(waveRow0 + r) * HD + qd * 8;
#pragma unroll
        for (int kc = 0; kc < 4; ++kc) {
            float x[8];
            *(float4*)&x[0] = *(const float4*)(qp + kc * 32);
            *(float4*)&x[4] = *(const float4*)(qp + kc * 32 + 4);
#pragma unroll
            for (int j = 0; j < 8; ++j) {
                ushort h = bf16rne(x[j]);
                qfh[kc][j] = (short)h;
                qfl[kc][j] = (short)bf16rne(x[j] - bf2f(h));
            }
        }
    }

    floatx4 oacc[8];
#pragma unroll
    for (int n = 0; n < 8; ++n) oacc[n] = (floatx4){0.f, 0.f, 0.f, 0.f};
    float m2[4] = {-INFINITY, -INFINITY, -INFINITY, -INFINITY};
    float lr[4] = {0.f, 0.f, 0.f, 0.f};

#define STAGE(tt, vs) do { \
        const ushort* _sK = kvw + (size_t)(tt) * TILE_USH; \
        const ushort* _sV = _sK + 16384; \
        _Pragma("unroll") \
        for (int _i = 0; _i < 8; ++_i) \
            __builtin_amdgcn_global_load_lds((glb_u32*)(_sK + (_i * 256 + tid) * 8), \
                (lds_u32*)&kbuf[(_i * 256 + wave * 64) * 8], 16, 0, 0); \
        _Pragma("unroll") \
        for (int _i = 0; _i < 4; ++_i) \
            __builtin_amdgcn_global_load_lds((glb_u32*)(_sV + (_i * 256 + tid) * 8), \
                (lds_u32*)&vbuf[vs][(_i * 256 + wave * 64) * 8], 16, 0, 0); \
    } while (0)

    STAGE(0, 0);

    for (int t = 0; t < 64; ++t) {
        __syncthreads();   // B1: drains DMA(t) [vmcnt(0)]; PV(t-1) V-reads done

        const ushort* KH = kbuf;
        const ushort* KL = kbuf + 8192;
        const int v0 = t * 64;

        // ---- QK^T(t) over this wave's 32 cols: 3-term bf16-split MFMA ----
        floatx4 cf[2];
        cf[0] = (floatx4){0.f, 0.f, 0.f, 0.f};
        cf[1] = (floatx4){0.f, 0.f, 0.f, 0.f};
#pragma unroll
        for (int kc = 0; kc < 4; ++kc) {
#pragma unroll
            for (int nb = 0; nb < 2; ++nb) {
                int ch = CHK_K(cw * 32 + nb * 16 + r, kc * 4 + qd);
                short8 kh = *(const short8*)&KH[ch];
                short8 kl = *(const short8*)&KL[ch];
                cf[nb] = __builtin_amdgcn_mfma_f32_16x16x32_bf16(qfh[kc], kh, cf[nb], 0, 0, 0);
                cf[nb] = __builtin_amdgcn_mfma_f32_16x16x32_bf16(qfh[kc], kl, cf[nb], 0, 0, 0);
                cf[nb] = __builtin_amdgcn_mfma_f32_16x16x32_bf16(qfl[kc], kh, cf[nb], 0, 0, 0);
            }
        }

        // ---- local softmax partials (per row, over this wave's 32 cols) ----
        float ts[2][4], pp[2][4], tm[4], sp[4];
#pragma unroll
        for (int nb = 0; nb < 2; ++nb)
#pragma unroll
            for (int g = 0; g < 4; ++g) ts[nb][g] = cf[nb][g] * SCL2E;
#pragma unroll
        for (int g = 0; g < 4; ++g) {
            float tmx = row_max16(fmaxf(ts[0][g], ts[1][g]));
            tm[g] = tmx;
            float s = 0.f;
#pragma unroll
            for (int nb = 0; nb < 2; ++nb) {
                pp[nb][g] = __builtin_amdgcn_exp2f(ts[nb][g] - tmx);
                s += pp[nb][g];
            }
            sp[g] = row_sum16(s);
        }
        if (r == 0) {
#pragma unroll
            for (int g = 0; g < 4; ++g) {
                mrow[wave][(qd * 4 + g) * 2]     = tm[g];
                mrow[wave][(qd * 4 + g) * 2 + 1] = sp[g];
            }
        }
        __syncthreads();   // B2: mrow visible; QK reads of kbuf done (no vmem pending)

        if (t < 63) STAGE(t + 1, (t + 1) & 1);   // K(t+1) may overwrite kbuf now

        // ---- pair merge + online update (both waves compute identically) ----
        float alpha[4], beta[4];
        bool rowneed = false;
#pragma unroll
        for (int g = 0; g < 4; ++g) {
            float mo = mrow[wave ^ 1][(qd * 4 + g) * 2];
            float so = mrow[wave ^ 1][(qd * 4 + g) * 2 + 1];
            float mt = fmaxf(tm[g], mo);
            float mn = fmaxf(m2[g], mt);
            alpha[g] = __builtin_amdgcn_exp2f(m2[g] - mn);
            beta[g]  = __builtin_amdgcn_exp2f(tm[g] - mn);
            float tsum = sp[g] * beta[g] + so * __builtin_amdgcn_exp2f(mo - mn);
            float lnew = lr[g] * alpha[g] + tsum;
            lr[g] = lnew;
            m2[g] = mn;
            rowneed |= (tsum > EPS_SKIP * lnew);
        }

        if (__any(rowneed)) {
            // rescale O (alpha==1 exactly on skipped tiles)
#pragma unroll
            for (int n = 0; n < 8; ++n)
#pragma unroll
                for (int g = 0; g < 4; ++g) oacc[n][g] *= alpha[g];

            // dropout, gated per (nb,g) granule (4 rows x 16 cols)
#pragma unroll
            for (int nb = 0; nb < 2; ++nb) {
#pragma unroll
                for (int g = 0; g < 4; ++g) {
                    float pf = pp[nb][g] * beta[g];
                    if (__any(pf > EPS_SKIP * lr[g])) {
                        uint j = (uint)(waveRow0 + qd * 4 + g) * (uint)NV
                               + (uint)(v0 + cw * 32 + nb * 16 + r);
                        if (threefry_bits(j) >= KEEP_THRESH) pf = 0.f;
                    }
                    // bf16 truncation (1 op; ~0.2% downward bias, within budget)
                    pls[wave][(qd * 4 + g) * PSTR2 + nb * 16 + r] =
                        (ushort)(__float_as_uint(pf) >> 16);
                }
            }
            __asm__ volatile("s_waitcnt lgkmcnt(0)" ::: "memory");  // own-wave P visible

            // ---- PV(t) over this wave's 32 v's: one K=32 MFMA per n ----
            const ushort* VT = vbuf[t & 1];
            short8 pa = *(const short8*)&pls[wave][r * PSTR2 + qd * 8];
#pragma unroll
            for (int n = 0; n < 8; ++n) {
                short8 vb = *(const short8*)&VT[CHK_V(n * 16 + r, cw * 4 + qd)];
                oacc[n] = __builtin_amdgcn_mfma_f32_16x16x32_bf16(pa, vb, oacc[n], 0, 0, 0);
            }
        }
    }
#undef STAGE

    // ---- epilogue: sum wave-pair partial O via kbuf (free now), normalize ----
    float* ob = (float*)&kbuf[0];   // 2 rg x 16 rows x 128 cols = 16 KB
    if (cw == 1) {
#pragma unroll
        for (int n = 0; n < 8; ++n)
#pragma unroll
            for (int g = 0; g < 4; ++g)
                ob[rg * 2048 + (qd * 4 + g) * 128 + n * 16 + r] = oacc[n][g];
    }
    __syncthreads();
    if (cw == 0) {
        float inv[4];
#pragma unroll
        for (int g = 0; g < 4; ++g) inv[g] = 1.0f / (0.9f * lr[g]);
#pragma unroll
        for (int n = 0; n < 8; ++n)
#pragma unroll
            for (int g = 0; g < 4; ++g) {
                float o = oacc[n][g] + ob[rg * 2048 + (qd * 4 + g) * 128 + n * 16 + r];
                Og[(size_t)(waveRow0 + qd * 4 + g) * HD + n * 16 + r] = o * inv[g];
            }
    }
}

// ============================ fused cooperative kernel ============================
__global__ __launch_bounds__(256, 2)
void fa_fused(const float* __restrict__ Qg, const float* __restrict__ Kg,
              const float* __restrict__ Vg, ushort* __restrict__ W,
              float* __restrict__ Og) {
    __shared__ __align__(16) ushort kbuf[16384];     // 32 KB (phase1 vls aliases here)
    __shared__ __align__(16) ushort vbuf[2][8192];   // 32 KB
    __shared__ ushort pls[4][16 * PSTR2];            // 5 KB
    __shared__ float mrow[4][32];

    const int tid = threadIdx.x;
    // phase 1: convert this block's unit (512 units over 512 blocks)
    prepass_body(Kg, Vg, W, blockIdx.x, tid, kbuf);
    // grid-wide barrier: all converted data visible device-wide
    cg::this_grid().sync();
    // phase 2: attention
    fa_body(Qg, (const ushort*)W, Og, blockIdx.x, tid, kbuf, vbuf, pls, mrow);
}

// ============================ two-dispatch path (round-7, verified) ============================
__global__ __launch_bounds__(256)
void prepass(const float* __restrict__ Kg, const float* __restrict__ Vg,
             ushort* __restrict__ W) {
    __shared__ ushort vls[64 * VLSTR];
    prepass_body(Kg, Vg, W, blockIdx.x, threadIdx.x, vls);
}

__global__ __launch_bounds__(256, 2)
void fa_mfma5(const float* __restrict__ Qg, const ushort* __restrict__ Wk,
              float* __restrict__ Og) {
    __shared__ __align__(16) ushort kbuf[16384];
    __shared__ __align__(16) ushort vbuf[2][8192];
    __shared__ ushort pls[4][16 * PSTR2];
    __shared__ float mrow[4][32];
    fa_body(Qg, Wk, Og, blockIdx.x, threadIdx.x, kbuf, vbuf, pls, mrow);
}

// ============================ fallback (round-3, verified) ============================
__global__ __launch_bounds__(256)
void fa_mfma(const float* __restrict__ Qg, const float* __restrict__ Kg,
             const float* __restrict__ Vg, float* __restrict__ Og) {
    __shared__ ushort khi[64 * KSTR];
    __shared__ ushort klo[64 * KSTR];
    __shared__ ushort vt[128 * VSTR];
    __shared__ ushort plsf[4][16 * PSTR];

    const int tid  = threadIdx.x;
    const int wave = tid >> 6;
    const int lane = tid & 63;
    const int r    = lane & 15;
    const int qd   = lane >> 4;
    const int blockRow0 = blockIdx.x * 64;
    const int b = blockRow0 >> 12;
    const int waveRow0 = blockRow0 + wave * 16;
    const size_t kvbase = (size_t)b * NV * HD;

    short8 qfh[4], qfl[4];
    {
        const float* qp = Qg + (size_t)(waveRow0 + r) * HD + qd * 8;
#pragma unroll
        for (int kc = 0; kc < 4; ++kc) {
            float x[8];
            *(float4*)&x[0] = *(const float4*)(qp + kc * 32);
            *(float4*)&x[4] = *(const float4*)(qp + kc * 32 + 4);
#pragma unroll
            for (int j = 0; j < 8; ++j) {
                ushort h = bf16rne(x[j]);
                qfh[kc][j] = (short)h;
                qfl[kc][j] = (short)bf16rne(x[j] - bf2f(h));
            }
        }
    }

    floatx4 oacc[8];
#pragma unroll
    for (int n = 0; n < 8; ++n) oacc[n] = (floatx4){0.f, 0.f, 0.f, 0.f};
    float m2[4] = {-INFINITY, -INFINITY, -INFINITY, -INFINITY};
    float lr[4] = {0.f, 0.f, 0.f, 0.f};

    for (int v0 = 0; v0 < NV; v0 += 64) {
        __syncthreads();
#pragma unroll
        for (int i = 0; i < 8; ++i) {
            int f = i * 256 + tid;
            int v = f >> 5;
            int h = (f & 31) * 4;
            float4 kv = *(const float4*)(Kg + kvbase + (size_t)(v0 + v) * HD + h);
            ushort4 hh, ll;
            hh.x = bf16rne(kv.x); ll.x = bf16rne(kv.x - bf2f(hh.x));
            hh.y = bf16rne(kv.y); ll.y = bf16rne(kv.y - bf2f(hh.y));
            hh.z = bf16rne(kv.z); ll.z = bf16rne(kv.z - bf2f(hh.z));
            hh.w = bf16rne(kv.w); ll.w = bf16rne(kv.w - bf2f(hh.w));
            *(ushort4*)&khi[v * KSTR + h] = hh;
            *(ushort4*)&klo[v * KSTR + h] = ll;
        }
        {
            int hp = tid & 63, rp = tid >> 6;
            int h = hp * 2;
            const float* vpb = Vg + kvbase + (size_t)v0 * HD + h;
#pragma unroll
            for (int i = 0; i < 8; ++i) {
                int v = i * 8 + rp * 2;
                float2 a = *(const float2*)(vpb + (size_t)v * HD);
                float2 c = *(const float2*)(vpb + (size_t)(v + 1) * HD);
                uint w0 = (uint)bf16rne(a.x) | ((uint)bf16rne(c.x) << 16);
                uint w1 = (uint)bf16rne(a.y) | ((uint)bf16rne(c.y) << 16);
                *(uint*)&vt[h * VSTR + v]       = w0;
                *(uint*)&vt[(h + 1) * VSTR + v] = w1;
            }
        }
        __syncthreads();

        floatx4 cf[4];
#pragma unroll
        for (int nb = 0; nb < 4; ++nb) cf[nb] = (floatx4){0.f, 0.f, 0.f, 0.f};
#pragma unroll
        for (int kc = 0; kc < 4; ++kc) {
#pragma unroll
            for (int nb = 0; nb < 4; ++nb) {
                int off = (nb * 16 + r) * KSTR + kc * 32 + qd * 8;
                short8 kh = *(const short8*)&khi[off];
                short8 kl = *(const short8*)&klo[off];
                cf[nb] = __builtin_amdgcn_mfma_f32_16x16x32_bf16(qfh[kc], kh, cf[nb], 0, 0, 0);
                cf[nb] = __builtin_amdgcn_mfma_f32_16x16x32_bf16(qfh[kc], kl, cf[nb], 0, 0, 0);
                cf[nb] = __builtin_amdgcn_mfma_f32_16x16x32_bf16(qfl[kc], kh, cf[nb], 0, 0, 0);
            }
        }

        float ts[4][4], p[4][4];
#pragma unroll
        for (int nb = 0; nb < 4; ++nb)
#pragma unroll
            for (int g = 0; g < 4; ++g) ts[nb][g] = cf[nb][g] * SCL2E;

        float tsum[4], alpha[4], lnew[4];
#pragma unroll
        for (int g = 0; g < 4; ++g) {
            float tmx = fmaxf(fmaxf(ts[0][g], ts[1][g]), fmaxf(ts[2][g], ts[3][g]));
#pragma unroll
            for (int off = 1; off < 16; off <<= 1)
                tmx = fmaxf(tmx, __shfl_xor(tmx, off));
            float mn = fmaxf(m2[g], tmx);
            alpha[g] = __builtin_amdgcn_exp2f(m2[g] - mn);
            m2[g] = mn;
        }
#pragma unroll
        for (int g = 0; g < 4; ++g) {
            float s = 0.f;
#pragma unroll
            for (int nb = 0; nb < 4; ++nb) {
                p[nb][g] = __builtin_amdgcn_exp2f(ts[nb][g] - m2[g]);
                s += p[nb][g];
            }
#pragma unroll
            for (int off = 1; off < 16; off <<= 1)
                s += __shfl_xor(s, off);
            tsum[g] = s;
            lnew[g] = lr[g] * alpha[g] + s;
            lr[g] = lnew[g];
        }

        bool rowneed = false;
#pragma unroll
        for (int g = 0; g < 4; ++g) rowneed |= (tsum[g] > 1e-8f * lnew[g]);

        if (__any(rowneed)) {
#pragma unroll
            for (int n = 0; n < 8; ++n)
#pragma unroll
                for (int g = 0; g < 4; ++g) oacc[n][g] *= alpha[g];

#pragma unroll
            for (int nb = 0; nb < 4; ++nb) {
                bool nbneed = false;
#pragma unroll
                for (int g = 0; g < 4; ++g) nbneed |= (p[nb][g] > 1e-8f * lnew[g]);
                if (__any(nbneed)) {
#pragma unroll
                    for (int g = 0; g < 4; ++g) {
                        uint j = (uint)(waveRow0 + qd * 4 + g) * (uint)NV
                               + (uint)(v0 + nb * 16 + r);
                        if (threefry_bits(j) >= KEEP_THRESH) p[nb][g] = 0.f;
                    }
                }
#pragma unroll
                for (int g = 0; g < 4; ++g)
                    plsf[wave][(qd * 4 + g) * PSTR + nb * 16 + r] = bf16rne(p[nb][g]);
            }
            __asm__ volatile("s_waitcnt lgkmcnt(0)" ::: "memory");

#pragma unroll
            for (int kc2 = 0; kc2 < 2; ++kc2) {
                short8 pa = *(const short8*)&plsf[wave][r * PSTR + kc2 * 32 + qd * 8];
#pragma unroll
                for (int n = 0; n < 8; ++n) {
                    int off = (n * 16 + r) * VSTR + kc2 * 32 + qd * 8;
                    ushort4 u0 = *(const ushort4*)&vt[off];
                    ushort4 u1 = *(const ushort4*)&vt[off + 4];
                    short8 vb;
                    vb[0] = (short)u0.x; vb[1] = (short)u0.y; vb[2] = (short)u0.z; vb[3] = (short)u0.w;
                    vb[4] = (short)u1.x; vb[5] = (short)u1.y; vb[6] = (short)u1.z; vb[7] = (short)u1.w;
                    oacc[n] = __builtin_amdgcn_mfma_f32_16x16x32_bf16(pa, vb, oacc[n], 0, 0, 0);
                }
            }
        }
    }

    float inv[4];
#pragma unroll
    for (int g = 0; g < 4; ++g) inv[g] = 1.0f / (0.9f * lr[g]);
#pragma unroll
    for (int n = 0; n < 8; ++n)
#pragma unroll
        for (int g = 0; g < 4; ++g)
            Og[(size_t)(waveRow0 + qd * 4 + g) * HD + n * 16 + r] = oacc[n][g] * inv[g];
}

extern "C" void kernel_launch(void* const* d_in, const int* in_sizes, int n_in,
                              void* d_out, int out_size, void* d_ws, size_t ws_size,
                              hipStream_t stream) {
    (void)in_sizes; (void)n_in; (void)out_size;
    const float* Qg = (const float*)d_in[0];
    const float* Kg = (const float*)d_in[1];
    const float* Vg = (const float*)d_in[2];
    float* Og = (float*)d_out;
    if (ws_size >= WS_NEEDED) {
        ushort* W = (ushort*)d_ws;
        void* kargs[] = { (void*)&Qg, (void*)&Kg, (void*)&Vg, (void*)&W, (void*)&Og };
        hipError_t e = hipLaunchCooperativeKernel((const void*)fa_fused,
                                                  dim3(NBATCH * NQ / 32), dim3(256),
                                                  kargs, 0, stream);
        if (e != hipSuccess) {
            // verified two-dispatch path
            prepass<<<dim3(512), 256, 0, stream>>>(Kg, Vg, W);
            fa_mfma5<<<dim3(NBATCH * NQ / 32), 256, 0, stream>>>(Qg, (const ushort*)W, Og);
        }
    } else {
        fa_mfma<<<dim3(NBATCH * NQ / 64), 256, 0, stream>>>(Qg, Kg, Vg, Og);
    }
}

// Round 9
// 247.242 us; speedup vs baseline: 1.2533x; 1.2533x over previous
//
#include <hip/hip_runtime.h>
#include <stdint.h>

// B=4, Q=4096, V=4096, H=128, fp32 in/out
#define NBATCH 4
#define NQ 4096
#define NV 4096
#define HD 128

// SCALE * log2(e): scores scaled into exp2 domain
#define SCL2E ((float)(11.31370849898476 * 1.4426950408889634))

// keep  <=>  bits < 0.9f in fixed point (0.9f = 7549747 * 2^-23)
#define KEEP_THRESH 3865470464u
#define EPS_SKIP 1e-6f

// --- ws layout (prepass output), FRAG-MAJOR ---
// per (batch,tile) record: [khi 8192 ush][klo 8192 ush][vt 8192 ush] = 48 KB
// chunk = 8 ushorts = 16B, 64 chunks per wave-instruction (1 KB coalesced).
// K chunk index for frag (kc 0..3, nb 0..3, lane): (kc*4+nb)*64 + lane,
//   lane = qd*16 + r holds K[v = nb*16+r][kc*32 + qd*8 ..+8]
// V chunk index for frag (kc2 0..1, n 0..7, lane): (kc2*8+n)*64 + lane,
//   lane = qd*16 + r holds V^T[h = n*16+r][kc2*32 + qd*8 ..+8]
#define TILE_USH 24576
#define WS_NEEDED ((size_t)NBATCH * 64 * TILE_USH * 2)       // 12,582,912 B

#define PSTR 72    // pls row stride (ushorts)
#define VLSTR 142  // prepass LDS v-tile stride (ushorts)

// --- fallback path constants (round-3 kernel, verified passing) ---
#define KSTR 144
#define VSTR 76

typedef __attribute__((ext_vector_type(8))) short short8;   // 8 bf16 (MFMA A/B frag)
typedef __attribute__((ext_vector_type(4))) float floatx4;  // MFMA C/D frag
typedef unsigned int uint;
typedef unsigned short ushort;

__device__ __forceinline__ ushort bf16rne(float f) {
    uint u = __float_as_uint(f);
    u = (u + 0x7fffu + ((u >> 16) & 1u)) >> 16;
    return (ushort)u;
}
__device__ __forceinline__ float bf2f(ushort h) {
    return __uint_as_float(((uint)h) << 16);
}

// ---- DPP 16-lane reductions (VALU-only, no DS pipe) ----
template <int CTRL>
__device__ __forceinline__ float dppmov(float x) {
    return __int_as_float(__builtin_amdgcn_update_dpp(
        0, __float_as_int(x), CTRL, 0xF, 0xF, true));
}
__device__ __forceinline__ float row_max16(float x) {
    x = fmaxf(x, dppmov<0xB1>(x));    // quad_perm xor1
    x = fmaxf(x, dppmov<0x4E>(x));    // quad_perm xor2
    x = fmaxf(x, dppmov<0x141>(x));   // row_half_mirror
    x = fmaxf(x, dppmov<0x140>(x));   // row_mirror
    return x;
}
__device__ __forceinline__ float row_sum16(float x) {
    x += dppmov<0xB1>(x);
    x += dppmov<0x4E>(x);
    x += dppmov<0x141>(x);
    x += dppmov<0x140>(x);
    return x;
}

__device__ __forceinline__ uint rotl(uint x, int r) { return (x << r) | (x >> (32 - r)); }

// JAX threefry2x32 partitionable path, key=(0,42): bits = y0 ^ y1 of hash of 64-bit counter j
__device__ __forceinline__ uint threefry_bits(uint j) {
    uint x0 = 0u;   // counter hi word (all j < 2^32)
    uint x1 = j;
    const uint k0 = 0u, k1 = 42u, k2 = 0u ^ 42u ^ 0x1BD11BDAu;
    x0 += k0; x1 += k1;
#define TFR4(a,b,c,d) \
    x0 += x1; x1 = rotl(x1, a); x1 ^= x0; \
    x0 += x1; x1 = rotl(x1, b); x1 ^= x0; \
    x0 += x1; x1 = rotl(x1, c); x1 ^= x0; \
    x0 += x1; x1 = rotl(x1, d); x1 ^= x0;
    TFR4(13, 15, 26, 6)
    x0 += k1; x1 += k2 + 1u;
    TFR4(17, 29, 16, 24)
    x0 += k2; x1 += k0 + 2u;
    TFR4(13, 15, 26, 6)
    x0 += k0; x1 += k1 + 3u;
    TFR4(17, 29, 16, 24)
    x0 += k1; x1 += k2 + 4u;
    TFR4(13, 15, 26, 6)
    x0 += k2; x1 += k0 + 5u;
#undef TFR4
    return x0 ^ x1;
}

// ============================ prepass ============================
// grid 512 = (4 batches x 64 tiles) x 2 halves. half 0: K convert; half 1: V transpose.
// Output positions are FRAG-MAJOR (see ws layout above). 16B global writes are
// scattered within the 48KB record; every byte gets written so L2 lines fill fully.
__global__ __launch_bounds__(256)
void prepass(const float* __restrict__ Kg, const float* __restrict__ Vg,
             ushort* __restrict__ W) {
    __shared__ ushort vls[64 * VLSTR];
    const int rec  = blockIdx.x >> 1;
    const int half = blockIdx.x & 1;
    const int bb = rec >> 6;
    const int t  = rec & 63;
    const int v0 = t * 64;
    const size_t kvbase = (size_t)bb * NV * HD;
    ushort* dst = W + ((size_t)bb * 64 + t) * TILE_USH;
    const int tid = threadIdx.x;

    if (half == 0) {
        // K: 1024 chunks (v 0..63, c 0..15), hi/lo split, coalesced reads
        ushort* dkh = dst;
        ushort* dkl = dst + 8192;
#pragma unroll
        for (int i = 0; i < 4; ++i) {
            int lc = i * 256 + tid;
            int v = lc >> 4, c = lc & 15;
            const float* src = Kg + kvbase + (size_t)(v0 + v) * HD + c * 8;
            float x[8];
            *(float4*)&x[0] = *(const float4*)src;
            *(float4*)&x[4] = *(const float4*)(src + 4);
            uint H[4], L[4];
#pragma unroll
            for (int k = 0; k < 4; ++k) {
                ushort h0 = bf16rne(x[2 * k]),     h1 = bf16rne(x[2 * k + 1]);
                ushort l0 = bf16rne(x[2 * k] - bf2f(h0));
                ushort l1 = bf16rne(x[2 * k + 1] - bf2f(h1));
                H[k] = (uint)h0 | ((uint)h1 << 16);
                L[k] = (uint)l0 | ((uint)l1 << 16);
            }
            // frag-major: kc=c>>2, qd=c&3, nb=v>>4, r=v&15
            int pos = (((c >> 2) * 4 + (v >> 4)) * 64 + (c & 3) * 16 + (v & 15)) * 8;
            *(uint4*)&dkh[pos] = *(uint4*)H;
            *(uint4*)&dkl[pos] = *(uint4*)L;
        }
    } else {
        // V phase A: coalesced float4 row reads -> bf16 LDS tile [v][h]
        ushort* dvt = dst + 16384;
#pragma unroll
        for (int i = 0; i < 8; ++i) {
            int idx = i * 256 + tid;
            int v = idx >> 5, hq = idx & 31;
            float4 a = *(const float4*)(Vg + kvbase + (size_t)(v0 + v) * HD + hq * 4);
            uint w0 = (uint)bf16rne(a.x) | ((uint)bf16rne(a.y) << 16);
            uint w1 = (uint)bf16rne(a.z) | ((uint)bf16rne(a.w) << 16);
            *(uint*)&vls[v * VLSTR + hq * 4]     = w0;
            *(uint*)&vls[v * VLSTR + hq * 4 + 2] = w1;
        }
        __syncthreads();
        // V phase B: transposed reads, frag-major chunk writes
#pragma unroll
        for (int i = 0; i < 4; ++i) {
            int lc = i * 256 + tid;
            int h = lc >> 3, c2 = lc & 7;
            uint Wd[4];
#pragma unroll
            for (int m = 0; m < 8; m += 2) {
                ushort a  = vls[(c2 * 8 + m) * VLSTR + h];
                ushort b2 = vls[(c2 * 8 + m + 1) * VLSTR + h];
                Wd[m >> 1] = (uint)a | ((uint)b2 << 16);
            }
            // frag-major: kc2=c2>>2, qd=c2&3, n=h>>4, r=h&15
            int pos = (((c2 >> 2) * 8 + (h >> 4)) * 64 + (c2 & 3) * 16 + (h & 15)) * 8;
            *(uint4*)&dvt[pos] = *(uint4*)Wd;
        }
    }
}

// ============================ main (fast path) ============================
// grid 512 x 256 threads (4 waves), 32 q-rows/block, ~26 KB LDS -> 2 blocks/CU.
// Wave = rg*2 + th: rg = row group (16 rows), th = TILE PARITY — each wave
// processes 32 of the 64 tiles independently (NO barriers in the K-loop;
// all MFMA operands loaded register-direct from frag-major ws). Wave pairs
// merge their online-softmax partials ONCE at the end.
// Fragment layouts (gfx950 mfma_f32_16x16x32_bf16, m89/m120-verified):
//   A: lane holds A[m = lane&15][k = (lane>>4)*8 + j]
//   B: lane holds B[k = (lane>>4)*8 + j][n = lane&15]
//   C/D: lane holds D[row = (lane>>4)*4 + reg][col = lane&15]
__global__ __launch_bounds__(256, 2)
void fa_mfma6(const float* __restrict__ Qg, const ushort* __restrict__ Wk,
              float* __restrict__ Og) {
    __shared__ ushort pls[4][16 * PSTR];   // wave-local P transpose, 9.2 KB
    __shared__ float mbuf[2][16 * 128];    // th=1 partial O, 16 KB
    __shared__ float mlbuf[2][16][2];      // th=1 partial (m, l)

    const int tid  = threadIdx.x;
    const int wave = tid >> 6;
    const int lane = tid & 63;
    const int r    = lane & 15;
    const int qd   = lane >> 4;
    const int rg   = wave >> 1;   // row group
    const int th   = wave & 1;    // tile parity
    const int blockRow0 = blockIdx.x * 32;
    const int b = blockRow0 >> 12;
    const int waveRow0 = blockRow0 + rg * 16;
    const ushort* kvw = Wk + (size_t)b * 64 * TILE_USH;

    // Q -> A-fragments (hi/lo bf16 split), registers
    short8 qfh[4], qfl[4];
    {
        const float* qp = Qg + (size_t)(waveRow0 + r) * HD + qd * 8;
#pragma unroll
        for (int kc = 0; kc < 4; ++kc) {
            float x[8];
            *(float4*)&x[0] = *(const float4*)(qp + kc * 32);
            *(float4*)&x[4] = *(const float4*)(qp + kc * 32 + 4);
#pragma unroll
            for (int j = 0; j < 8; ++j) {
                ushort h = bf16rne(x[j]);
                qfh[kc][j] = (short)h;
                qfl[kc][j] = (short)bf16rne(x[j] - bf2f(h));
            }
        }
    }

    floatx4 oacc[8];
#pragma unroll
    for (int n = 0; n < 8; ++n) oacc[n] = (floatx4){0.f, 0.f, 0.f, 0.f};
    float m2[4] = {-INFINITY, -INFINITY, -INFINITY, -INFINITY};
    float lr[4] = {0.f, 0.f, 0.f, 0.f};

    for (int t = th; t < 64; t += 2) {
        const ushort* tK = kvw + (size_t)t * TILE_USH;
        const ushort* tV = tK + 16384;
        const int v0 = t * 64;

        // ---- QK^T(t): register-direct coalesced loads, 3-term bf16-split MFMA ----
        floatx4 cf[4];
#pragma unroll
        for (int nb = 0; nb < 4; ++nb) cf[nb] = (floatx4){0.f, 0.f, 0.f, 0.f};
#pragma unroll
        for (int kc = 0; kc < 4; ++kc) {
            short8 kh[4], kl[4];
#pragma unroll
            for (int nb = 0; nb < 4; ++nb) {
                int off = ((kc * 4 + nb) * 64 + lane) * 8;
                kh[nb] = *(const short8*)&tK[off];
                kl[nb] = *(const short8*)&tK[8192 + off];
            }
#pragma unroll
            for (int nb = 0; nb < 4; ++nb) {
                cf[nb] = __builtin_amdgcn_mfma_f32_16x16x32_bf16(qfh[kc], kh[nb], cf[nb], 0, 0, 0);
                cf[nb] = __builtin_amdgcn_mfma_f32_16x16x32_bf16(qfh[kc], kl[nb], cf[nb], 0, 0, 0);
                cf[nb] = __builtin_amdgcn_mfma_f32_16x16x32_bf16(qfl[kc], kh[nb], cf[nb], 0, 0, 0);
            }
        }

        // ---- online softmax (exp2 domain), DPP reductions ----
        float ts[4][4], p[4][4];
#pragma unroll
        for (int nb = 0; nb < 4; ++nb)
#pragma unroll
            for (int g = 0; g < 4; ++g) ts[nb][g] = cf[nb][g] * SCL2E;

        float tsum[4], alpha[4], lnew[4];
#pragma unroll
        for (int g = 0; g < 4; ++g) {
            float tmx = fmaxf(fmaxf(ts[0][g], ts[1][g]), fmaxf(ts[2][g], ts[3][g]));
            tmx = row_max16(tmx);
            float mn = fmaxf(m2[g], tmx);
            alpha[g] = __builtin_amdgcn_exp2f(m2[g] - mn);
            m2[g] = mn;
        }
#pragma unroll
        for (int g = 0; g < 4; ++g) {
            float s = 0.f;
#pragma unroll
            for (int nb = 0; nb < 4; ++nb) {
                p[nb][g] = __builtin_amdgcn_exp2f(ts[nb][g] - m2[g]);
                s += p[nb][g];
            }
            s = row_sum16(s);
            tsum[g] = s;
            lnew[g] = lr[g] * alpha[g] + s;
            lr[g] = lnew[g];
        }

        bool rowneed = false;
#pragma unroll
        for (int g = 0; g < 4; ++g) rowneed |= (tsum[g] > EPS_SKIP * lnew[g]);

        if (__any(rowneed)) {
            // rescale O (alpha==1 exactly on skipped tiles)
#pragma unroll
            for (int n = 0; n < 8; ++n)
#pragma unroll
                for (int g = 0; g < 4; ++g) oacc[n][g] *= alpha[g];

            // dropout, gated per (nb,g) granule; wave-local pls (no barrier needed)
#pragma unroll
            for (int nb = 0; nb < 4; ++nb) {
#pragma unroll
                for (int g = 0; g < 4; ++g) {
                    if (__any(p[nb][g] > EPS_SKIP * lnew[g])) {
                        uint j = (uint)(waveRow0 + qd * 4 + g) * (uint)NV
                               + (uint)(v0 + nb * 16 + r);
                        if (threefry_bits(j) >= KEEP_THRESH) p[nb][g] = 0.f;
                    }
                    // bf16 truncation (1 op; ~0.2% downward bias, within budget)
                    pls[wave][(qd * 4 + g) * PSTR + nb * 16 + r] =
                        (ushort)(__float_as_uint(p[nb][g]) >> 16);
                }
            }
            __asm__ volatile("s_waitcnt lgkmcnt(0)" ::: "memory");  // own-wave P visible

            // ---- PV(t): register-direct V frags, K=32 MFMAs ----
#pragma unroll
            for (int kc2 = 0; kc2 < 2; ++kc2) {
                short8 pa = *(const short8*)&pls[wave][r * PSTR + kc2 * 32 + qd * 8];
#pragma unroll
                for (int n = 0; n < 8; ++n) {
                    short8 vb = *(const short8*)&tV[((kc2 * 8 + n) * 64 + lane) * 8];
                    oacc[n] = __builtin_amdgcn_mfma_f32_16x16x32_bf16(pa, vb, oacc[n], 0, 0, 0);
                }
            }
        }
    }

    // ---- end merge of the tile-parity pair (single barrier in the kernel) ----
    if (th == 1) {
        if (r == 0) {
#pragma unroll
            for (int g = 0; g < 4; ++g) {
                mlbuf[rg][qd * 4 + g][0] = m2[g];
                mlbuf[rg][qd * 4 + g][1] = lr[g];
            }
        }
#pragma unroll
        for (int n = 0; n < 8; ++n)
#pragma unroll
            for (int g = 0; g < 4; ++g)
                mbuf[rg][(qd * 4 + g) * 128 + n * 16 + r] = oacc[n][g];
    }
    __syncthreads();
    if (th == 0) {
        float aA[4], aB[4], inv[4];
#pragma unroll
        for (int g = 0; g < 4; ++g) {
            float mo = mlbuf[rg][qd * 4 + g][0];
            float so = mlbuf[rg][qd * 4 + g][1];
            float mn = fmaxf(m2[g], mo);
            aA[g] = __builtin_amdgcn_exp2f(m2[g] - mn);
            aB[g] = __builtin_amdgcn_exp2f(mo - mn);
            float l = lr[g] * aA[g] + so * aB[g];
            inv[g] = 1.0f / (0.9f * l);
        }
#pragma unroll
        for (int n = 0; n < 8; ++n)
#pragma unroll
            for (int g = 0; g < 4; ++g) {
                float o = oacc[n][g] * aA[g]
                        + mbuf[rg][(qd * 4 + g) * 128 + n * 16 + r] * aB[g];
                Og[(size_t)(waveRow0 + qd * 4 + g) * HD + n * 16 + r] = o * inv[g];
            }
    }
}

// ============================ fallback (round-3, verified) ============================
__global__ __launch_bounds__(256)
void fa_mfma(const float* __restrict__ Qg, const float* __restrict__ Kg,
             const float* __restrict__ Vg, float* __restrict__ Og) {
    __shared__ ushort khi[64 * KSTR];
    __shared__ ushort klo[64 * KSTR];
    __shared__ ushort vt[128 * VSTR];
    __shared__ ushort plsf[4][16 * PSTR];

    const int tid  = threadIdx.x;
    const int wave = tid >> 6;
    const int lane = tid & 63;
    const int r    = lane & 15;
    const int qd   = lane >> 4;
    const int blockRow0 = blockIdx.x * 64;
    const int b = blockRow0 >> 12;
    const int waveRow0 = blockRow0 + wave * 16;
    const size_t kvbase = (size_t)b * NV * HD;

    short8 qfh[4], qfl[4];
    {
        const float* qp = Qg + (size_t)(waveRow0 + r) * HD + qd * 8;
#pragma unroll
        for (int kc = 0; kc < 4; ++kc) {
            float x[8];
            *(float4*)&x[0] = *(const float4*)(qp + kc * 32);
            *(float4*)&x[4] = *(const float4*)(qp + kc * 32 + 4);
#pragma unroll
            for (int j = 0; j < 8; ++j) {
                ushort h = bf16rne(x[j]);
                qfh[kc][j] = (short)h;
                qfl[kc][j] = (short)bf16rne(x[j] - bf2f(h));
            }
        }
    }

    floatx4 oacc[8];
#pragma unroll
    for (int n = 0; n < 8; ++n) oacc[n] = (floatx4){0.f, 0.f, 0.f, 0.f};
    float m2[4] = {-INFINITY, -INFINITY, -INFINITY, -INFINITY};
    float lr[4] = {0.f, 0.f, 0.f, 0.f};

    for (int v0 = 0; v0 < NV; v0 += 64) {
        __syncthreads();
#pragma unroll
        for (int i = 0; i < 8; ++i) {
            int f = i * 256 + tid;
            int v = f >> 5;
            int h = (f & 31) * 4;
            float4 kv = *(const float4*)(Kg + kvbase + (size_t)(v0 + v) * HD + h);
            ushort4 hh, ll;
            hh.x = bf16rne(kv.x); ll.x = bf16rne(kv.x - bf2f(hh.x));
            hh.y = bf16rne(kv.y); ll.y = bf16rne(kv.y - bf2f(hh.y));
            hh.z = bf16rne(kv.z); ll.z = bf16rne(kv.z - bf2f(hh.z));
            hh.w = bf16rne(kv.w); ll.w = bf16rne(kv.w - bf2f(hh.w));
            *(ushort4*)&khi[v * KSTR + h] = hh;
            *(ushort4*)&klo[v * KSTR + h] = ll;
        }
        {
            int hp = tid & 63, rp = tid >> 6;
            int h = hp * 2;
            const float* vpb = Vg + kvbase + (size_t)v0 * HD + h;
#pragma unroll
            for (int i = 0; i < 8; ++i) {
                int v = i * 8 + rp * 2;
                float2 a = *(const float2*)(vpb + (size_t)v * HD);
                float2 c = *(const float2*)(vpb + (size_t)(v + 1) * HD);
                uint w0 = (uint)bf16rne(a.x) | ((uint)bf16rne(c.x) << 16);
                uint w1 = (uint)bf16rne(a.y) | ((uint)bf16rne(c.y) << 16);
                *(uint*)&vt[h * VSTR + v]       = w0;
                *(uint*)&vt[(h + 1) * VSTR + v] = w1;
            }
        }
        __syncthreads();

        floatx4 cf[4];
#pragma unroll
        for (int nb = 0; nb < 4; ++nb) cf[nb] = (floatx4){0.f, 0.f, 0.f, 0.f};
#pragma unroll
        for (int kc = 0; kc < 4; ++kc) {
#pragma unroll
            for (int nb = 0; nb < 4; ++nb) {
                int off = (nb * 16 + r) * KSTR + kc * 32 + qd * 8;
                short8 kh = *(const short8*)&khi[off];
                short8 kl = *(const short8*)&klo[off];
                cf[nb] = __builtin_amdgcn_mfma_f32_16x16x32_bf16(qfh[kc], kh, cf[nb], 0, 0, 0);
                cf[nb] = __builtin_amdgcn_mfma_f32_16x16x32_bf16(qfh[kc], kl, cf[nb], 0, 0, 0);
                cf[nb] = __builtin_amdgcn_mfma_f32_16x16x32_bf16(qfl[kc], kh, cf[nb], 0, 0, 0);
            }
        }

        float ts[4][4], p[4][4];
#pragma unroll
        for (int nb = 0; nb < 4; ++nb)
#pragma unroll
            for (int g = 0; g < 4; ++g) ts[nb][g] = cf[nb][g] * SCL2E;

        float tsum[4], alpha[4], lnew[4];
#pragma unroll
        for (int g = 0; g < 4; ++g) {
            float tmx = fmaxf(fmaxf(ts[0][g], ts[1][g]), fmaxf(ts[2][g], ts[3][g]));
#pragma unroll
            for (int off = 1; off < 16; off <<= 1)
                tmx = fmaxf(tmx, __shfl_xor(tmx, off));
            float mn = fmaxf(m2[g], tmx);
            alpha[g] = __builtin_amdgcn_exp2f(m2[g] - mn);
            m2[g] = mn;
        }
#pragma unroll
        for (int g = 0; g < 4; ++g) {
            float s = 0.f;
#pragma unroll
            for (int nb = 0; nb < 4; ++nb) {
                p[nb][g] = __builtin_amdgcn_exp2f(ts[nb][g] - m2[g]);
                s += p[nb][g];
            }
#pragma unroll
            for (int off = 1; off < 16; off <<= 1)
                s += __shfl_xor(s, off);
            tsum[g] = s;
            lnew[g] = lr[g] * alpha[g] + s;
            lr[g] = lnew[g];
        }

        bool rowneed = false;
#pragma unroll
        for (int g = 0; g < 4; ++g) rowneed |= (tsum[g] > 1e-8f * lnew[g]);

        if (__any(rowneed)) {
#pragma unroll
            for (int n = 0; n < 8; ++n)
#pragma unroll
                for (int g = 0; g < 4; ++g) oacc[n][g] *= alpha[g];

#pragma unroll
            for (int nb = 0; nb < 4; ++nb) {
                bool nbneed = false;
#pragma unroll
                for (int g = 0; g < 4; ++g) nbneed |= (p[nb][g] > 1e-8f * lnew[g]);
                if (__any(nbneed)) {
#pragma unroll
                    for (int g = 0; g < 4; ++g) {
                        uint j = (uint)(waveRow0 + qd * 4 + g) * (uint)NV
                               + (uint)(v0 + nb * 16 + r);
                        if (threefry_bits(j) >= KEEP_THRESH) p[nb][g] = 0.f;
                    }
                }
#pragma unroll
                for (int g = 0; g < 4; ++g)
                    plsf[wave][(qd * 4 + g) * PSTR + nb * 16 + r] = bf16rne(p[nb][g]);
            }
            __asm__ volatile("s_waitcnt lgkmcnt(0)" ::: "memory");

#pragma unroll
            for (int kc2 = 0; kc2 < 2; ++kc2) {
                short8 pa = *(const short8*)&plsf[wave][r * PSTR + kc2 * 32 + qd * 8];
#pragma unroll
                for (int n = 0; n < 8; ++n) {
                    int off = (n * 16 + r) * VSTR + kc2 * 32 + qd * 8;
                    ushort4 u0 = *(const ushort4*)&vt[off];
                    ushort4 u1 = *(const ushort4*)&vt[off + 4];
                    short8 vb;
                    vb[0] = (short)u0.x; vb[1] = (short)u0.y; vb[2] = (short)u0.z; vb[3] = (short)u0.w;
                    vb[4] = (short)u1.x; vb[5] = (short)u1.y; vb[6] = (short)u1.z; vb[7] = (short)u1.w;
                    oacc[n] = __builtin_amdgcn_mfma_f32_16x16x32_bf16(pa, vb, oacc[n], 0, 0, 0);
                }
            }
        }
    }

    float inv[4];
#pragma unroll
    for (int g = 0; g < 4; ++g) inv[g] = 1.0f / (0.9f * lr[g]);
#pragma unroll
    for (int n = 0; n < 8; ++n)
#pragma unroll
        for (int g = 0; g < 4; ++g)
            Og[(size_t)(waveRow0 + qd * 4 + g) * HD + n * 16 + r] = oacc[n][g] * inv[g];
}

extern "C" void kernel_launch(void* const* d_in, const int* in_sizes, int n_in,
                              void* d_out, int out_size, void* d_ws, size_t ws_size,
                              hipStream_t stream) {
    (void)in_sizes; (void)n_in; (void)out_size;
    const float* Qg = (const float*)d_in[0];
    const float* Kg = (const float*)d_in[1];
    const float* Vg = (const float*)d_in[2];
    float* Og = (float*)d_out;
    if (ws_size >= WS_NEEDED) {
        ushort* W = (ushort*)d_ws;
        prepass<<<dim3(512), 256, 0, stream>>>(Kg, Vg, W);
        fa_mfma6<<<dim3(NBATCH * NQ / 32), 256, 0, stream>>>(Qg, (const ushort*)W, Og);
    } else {
        fa_mfma<<<dim3(NBATCH * NQ / 64), 256, 0, stream>>>(Qg, Kg, Vg, Og);
    }
}

// Round 10
// 198.149 us; speedup vs baseline: 1.5638x; 1.2478x over previous
//
#include <hip/hip_runtime.h>
#include <stdint.h>

// B=4, Q=4096, V=4096, H=128, fp32 in/out
#define NBATCH 4
#define NQ 4096
#define NV 4096
#define HD 128

// SCALE * log2(e): scores scaled into exp2 domain
#define SCL2E ((float)(11.31370849898476 * 1.4426950408889634))

// keep  <=>  bits < 0.9f in fixed point (0.9f = 7549747 * 2^-23)
#define KEEP_THRESH 3865470464u
#define EPS_SKIP 1e-6f

// --- ws layout (prepass output), FRAG-MAJOR (verified in round 9) ---
// per (batch,tile) record: [khi 8192 ush][klo 8192 ush][vt 8192 ush] = 48 KB
// chunk = 8 ushorts = 16B, 64 chunks per wave-instruction (1 KB coalesced).
// K chunk (kc,nb,lane): (kc*4+nb)*64+lane holds K[v=nb*16+r][kc*32+qd*8..+8]
// V chunk (kc2,n,lane): (kc2*8+n)*64+lane holds V^T[h=n*16+r][kc2*32+qd*8..+8]
#define TILE_USH 24576
#define WS_NEEDED ((size_t)NBATCH * 64 * TILE_USH * 2)       // 12,582,912 B

#define PSTR 72    // pls row stride (ushorts)
#define VLSTR 142  // prepass LDS v-tile stride (ushorts)

// --- fallback path constants (round-3 kernel, verified passing) ---
#define KSTR 144
#define VSTR 76

typedef __attribute__((ext_vector_type(8))) short short8;   // 8 bf16 (MFMA A/B frag)
typedef __attribute__((ext_vector_type(4))) float floatx4;  // MFMA C/D frag
typedef unsigned int uint;
typedef unsigned short ushort;

__device__ __forceinline__ ushort bf16rne(float f) {
    uint u = __float_as_uint(f);
    u = (u + 0x7fffu + ((u >> 16) & 1u)) >> 16;
    return (ushort)u;
}
__device__ __forceinline__ float bf2f(ushort h) {
    return __uint_as_float(((uint)h) << 16);
}

// ---- DPP 16-lane reductions (VALU-only, no DS pipe) ----
template <int CTRL>
__device__ __forceinline__ float dppmov(float x) {
    return __int_as_float(__builtin_amdgcn_update_dpp(
        0, __float_as_int(x), CTRL, 0xF, 0xF, true));
}
__device__ __forceinline__ float row_max16(float x) {
    x = fmaxf(x, dppmov<0xB1>(x));    // quad_perm xor1
    x = fmaxf(x, dppmov<0x4E>(x));    // quad_perm xor2
    x = fmaxf(x, dppmov<0x141>(x));   // row_half_mirror
    x = fmaxf(x, dppmov<0x140>(x));   // row_mirror
    return x;
}
__device__ __forceinline__ float row_sum16(float x) {
    x += dppmov<0xB1>(x);
    x += dppmov<0x4E>(x);
    x += dppmov<0x141>(x);
    x += dppmov<0x140>(x);
    return x;
}

__device__ __forceinline__ uint rotl(uint x, int r) { return (x << r) | (x >> (32 - r)); }

// JAX threefry2x32 partitionable path, key=(0,42): bits = y0 ^ y1 of hash of 64-bit counter j
__device__ __forceinline__ uint threefry_bits(uint j) {
    uint x0 = 0u;   // counter hi word (all j < 2^32)
    uint x1 = j;
    const uint k0 = 0u, k1 = 42u, k2 = 0u ^ 42u ^ 0x1BD11BDAu;
    x0 += k0; x1 += k1;
#define TFR4(a,b,c,d) \
    x0 += x1; x1 = rotl(x1, a); x1 ^= x0; \
    x0 += x1; x1 = rotl(x1, b); x1 ^= x0; \
    x0 += x1; x1 = rotl(x1, c); x1 ^= x0; \
    x0 += x1; x1 = rotl(x1, d); x1 ^= x0;
    TFR4(13, 15, 26, 6)
    x0 += k1; x1 += k2 + 1u;
    TFR4(17, 29, 16, 24)
    x0 += k2; x1 += k0 + 2u;
    TFR4(13, 15, 26, 6)
    x0 += k0; x1 += k1 + 3u;
    TFR4(17, 29, 16, 24)
    x0 += k1; x1 += k2 + 4u;
    TFR4(13, 15, 26, 6)
    x0 += k2; x1 += k0 + 5u;
#undef TFR4
    return x0 ^ x1;
}

// ============================ prepass (byte-identical to round 9, verified) ============================
__global__ __launch_bounds__(256)
void prepass(const float* __restrict__ Kg, const float* __restrict__ Vg,
             ushort* __restrict__ W) {
    __shared__ ushort vls[64 * VLSTR];
    const int rec  = blockIdx.x >> 1;
    const int half = blockIdx.x & 1;
    const int bb = rec >> 6;
    const int t  = rec & 63;
    const int v0 = t * 64;
    const size_t kvbase = (size_t)bb * NV * HD;
    ushort* dst = W + ((size_t)bb * 64 + t) * TILE_USH;
    const int tid = threadIdx.x;

    if (half == 0) {
        ushort* dkh = dst;
        ushort* dkl = dst + 8192;
#pragma unroll
        for (int i = 0; i < 4; ++i) {
            int lc = i * 256 + tid;
            int v = lc >> 4, c = lc & 15;
            const float* src = Kg + kvbase + (size_t)(v0 + v) * HD + c * 8;
            float x[8];
            *(float4*)&x[0] = *(const float4*)src;
            *(float4*)&x[4] = *(const float4*)(src + 4);
            uint H[4], L[4];
#pragma unroll
            for (int k = 0; k < 4; ++k) {
                ushort h0 = bf16rne(x[2 * k]),     h1 = bf16rne(x[2 * k + 1]);
                ushort l0 = bf16rne(x[2 * k] - bf2f(h0));
                ushort l1 = bf16rne(x[2 * k + 1] - bf2f(h1));
                H[k] = (uint)h0 | ((uint)h1 << 16);
                L[k] = (uint)l0 | ((uint)l1 << 16);
            }
            int pos = (((c >> 2) * 4 + (v >> 4)) * 64 + (c & 3) * 16 + (v & 15)) * 8;
            *(uint4*)&dkh[pos] = *(uint4*)H;
            *(uint4*)&dkl[pos] = *(uint4*)L;
        }
    } else {
        ushort* dvt = dst + 16384;
#pragma unroll
        for (int i = 0; i < 8; ++i) {
            int idx = i * 256 + tid;
            int v = idx >> 5, hq = idx & 31;
            float4 a = *(const float4*)(Vg + kvbase + (size_t)(v0 + v) * HD + hq * 4);
            uint w0 = (uint)bf16rne(a.x) | ((uint)bf16rne(a.y) << 16);
            uint w1 = (uint)bf16rne(a.z) | ((uint)bf16rne(a.w) << 16);
            *(uint*)&vls[v * VLSTR + hq * 4]     = w0;
            *(uint*)&vls[v * VLSTR + hq * 4 + 2] = w1;
        }
        __syncthreads();
#pragma unroll
        for (int i = 0; i < 4; ++i) {
            int lc = i * 256 + tid;
            int h = lc >> 3, c2 = lc & 7;
            uint Wd[4];
#pragma unroll
            for (int m = 0; m < 8; m += 2) {
                ushort a  = vls[(c2 * 8 + m) * VLSTR + h];
                ushort b2 = vls[(c2 * 8 + m + 1) * VLSTR + h];
                Wd[m >> 1] = (uint)a | ((uint)b2 << 16);
            }
            int pos = (((c2 >> 2) * 8 + (h >> 4)) * 64 + (c2 & 3) * 16 + (h & 15)) * 8;
            *(uint4*)&dvt[pos] = *(uint4*)Wd;
        }
    }
}

// ============================ main (fast path) ============================
// grid 512 x 256 threads (4 waves), 32 q-rows/block. Each wave carries ALL 32
// rows (two 16-row m-blocks) and processes tiles t = wave (mod 4): 16 tiles,
// fully independent, NO barriers in the K-loop, every MFMA operand loaded
// register-direct (coalesced global_load_dwordx4 from frag-major W). Each
// tile record is read ONCE per block (fixes r9's 2x L2 duplication).
// 4-way online-softmax merge once at the end.
// Fragment layouts (gfx950 mfma_f32_16x16x32_bf16, m89/m120-verified):
//   A: lane holds A[m = lane&15][k = (lane>>4)*8 + j]
//   B: lane holds B[k = (lane>>4)*8 + j][n = lane&15]
//   C/D: lane holds D[row = (lane>>4)*4 + reg][col = lane&15]
__global__ __launch_bounds__(256, 2)
void fa_mfma7(const float* __restrict__ Qg, const ushort* __restrict__ Wk,
              float* __restrict__ Og) {
    __shared__ ushort pls[4][32 * PSTR];   // wave-local P transpose, 18.4 KB
    __shared__ float obuf[3][32 * 128];    // waves 1-3 partial O, 48 KB
    __shared__ float mlbuf[3][32][2];      // waves 1-3 partial (m, l)

    const int tid  = threadIdx.x;
    const int wave = tid >> 6;    // tile phase
    const int lane = tid & 63;
    const int r    = lane & 15;
    const int qd   = lane >> 4;
    const int blockRow0 = blockIdx.x * 32;
    const int b = blockRow0 >> 12;
    const ushort* kvw = Wk + (size_t)b * 64 * TILE_USH;

    // Q -> A-fragments for both 16-row m-blocks (hi/lo bf16 split), registers
    short8 qfh[2][4], qfl[2][4];
#pragma unroll
    for (int mr = 0; mr < 2; ++mr) {
        const float* qp = Qg + (size_t)(blockRow0 + mr * 16 + r) * HD + qd * 8;
#pragma unroll
        for (int kc = 0; kc < 4; ++kc) {
            float x[8];
            *(float4*)&x[0] = *(const float4*)(qp + kc * 32);
            *(float4*)&x[4] = *(const float4*)(qp + kc * 32 + 4);
#pragma unroll
            for (int j = 0; j < 8; ++j) {
                ushort h = bf16rne(x[j]);
                qfh[mr][kc][j] = (short)h;
                qfl[mr][kc][j] = (short)bf16rne(x[j] - bf2f(h));
            }
        }
    }

    floatx4 oacc[2][8];
#pragma unroll
    for (int mr = 0; mr < 2; ++mr)
#pragma unroll
        for (int n = 0; n < 8; ++n) oacc[mr][n] = (floatx4){0.f, 0.f, 0.f, 0.f};
    float m2[2][4], lr[2][4];
#pragma unroll
    for (int mr = 0; mr < 2; ++mr)
#pragma unroll
        for (int g = 0; g < 4; ++g) { m2[mr][g] = -INFINITY; lr[mr][g] = 0.f; }

    for (int t = wave; t < 64; t += 4) {
        const ushort* tK = kvw + (size_t)t * TILE_USH;
        const ushort* tV = tK + 16384;
        const int v0 = t * 64;

        // ---- QK^T(t): register-direct loads, 3-term bf16-split, both m-blocks ----
        floatx4 cf[2][4];
#pragma unroll
        for (int mr = 0; mr < 2; ++mr)
#pragma unroll
            for (int nb = 0; nb < 4; ++nb) cf[mr][nb] = (floatx4){0.f, 0.f, 0.f, 0.f};
#pragma unroll
        for (int kc = 0; kc < 4; ++kc) {
            short8 kh[4], kl[4];
#pragma unroll
            for (int nb = 0; nb < 4; ++nb) {
                int off = ((kc * 4 + nb) * 64 + lane) * 8;
                kh[nb] = *(const short8*)&tK[off];
                kl[nb] = *(const short8*)&tK[8192 + off];
            }
#pragma unroll
            for (int nb = 0; nb < 4; ++nb)
#pragma unroll
                for (int mr = 0; mr < 2; ++mr) {
                    cf[mr][nb] = __builtin_amdgcn_mfma_f32_16x16x32_bf16(qfh[mr][kc], kh[nb], cf[mr][nb], 0, 0, 0);
                    cf[mr][nb] = __builtin_amdgcn_mfma_f32_16x16x32_bf16(qfh[mr][kc], kl[nb], cf[mr][nb], 0, 0, 0);
                    cf[mr][nb] = __builtin_amdgcn_mfma_f32_16x16x32_bf16(qfl[mr][kc], kh[nb], cf[mr][nb], 0, 0, 0);
                }
        }

        // ---- online softmax (exp2 domain), DPP reductions, per m-block ----
        bool act[2];
#pragma unroll
        for (int mr = 0; mr < 2; ++mr) {
            float ts[4][4], p[4][4], alpha[4], lnew[4], tsum[4];
#pragma unroll
            for (int nb = 0; nb < 4; ++nb)
#pragma unroll
                for (int g = 0; g < 4; ++g) ts[nb][g] = cf[mr][nb][g] * SCL2E;
#pragma unroll
            for (int g = 0; g < 4; ++g) {
                float tmx = fmaxf(fmaxf(ts[0][g], ts[1][g]), fmaxf(ts[2][g], ts[3][g]));
                tmx = row_max16(tmx);
                float mn = fmaxf(m2[mr][g], tmx);
                alpha[g] = __builtin_amdgcn_exp2f(m2[mr][g] - mn);
                m2[mr][g] = mn;
            }
#pragma unroll
            for (int g = 0; g < 4; ++g) {
                float s = 0.f;
#pragma unroll
                for (int nb = 0; nb < 4; ++nb) {
                    p[nb][g] = __builtin_amdgcn_exp2f(ts[nb][g] - m2[mr][g]);
                    s += p[nb][g];
                }
                s = row_sum16(s);
                tsum[g] = s;
                lnew[g] = lr[mr][g] * alpha[g] + s;
                lr[mr][g] = lnew[g];
            }
            bool rowneed = false;
#pragma unroll
            for (int g = 0; g < 4; ++g) rowneed |= (tsum[g] > EPS_SKIP * lnew[g]);
            act[mr] = __any(rowneed);

            if (act[mr]) {
                // rescale O (alpha==1 exactly on skipped tiles)
#pragma unroll
                for (int n = 0; n < 8; ++n)
#pragma unroll
                    for (int g = 0; g < 4; ++g) oacc[mr][n][g] *= alpha[g];
                // dropout, gated per (nb,g) granule; write P for PV
#pragma unroll
                for (int nb = 0; nb < 4; ++nb) {
#pragma unroll
                    for (int g = 0; g < 4; ++g) {
                        if (__any(p[nb][g] > EPS_SKIP * lnew[g])) {
                            uint j = (uint)(blockRow0 + mr * 16 + qd * 4 + g) * (uint)NV
                                   + (uint)(v0 + nb * 16 + r);
                            if (threefry_bits(j) >= KEEP_THRESH) p[nb][g] = 0.f;
                        }
                        // bf16 truncation (1 op; ~0.2% downward bias, within budget)
                        pls[wave][(mr * 16 + qd * 4 + g) * PSTR + nb * 16 + r] =
                            (ushort)(__float_as_uint(p[nb][g]) >> 16);
                    }
                }
            }
        }

        if (act[0] | act[1]) {
            __asm__ volatile("s_waitcnt lgkmcnt(0)" ::: "memory");  // own-wave P visible
            // ---- PV(t): register-direct V frags, K=32 MFMAs per m-block ----
#pragma unroll
            for (int mr = 0; mr < 2; ++mr) {
                if (!act[mr]) continue;
#pragma unroll
                for (int kc2 = 0; kc2 < 2; ++kc2) {
                    short8 pa = *(const short8*)&pls[wave][(mr * 16 + r) * PSTR + kc2 * 32 + qd * 8];
#pragma unroll
                    for (int n = 0; n < 8; ++n) {
                        short8 vb = *(const short8*)&tV[((kc2 * 8 + n) * 64 + lane) * 8];
                        oacc[mr][n] = __builtin_amdgcn_mfma_f32_16x16x32_bf16(pa, vb, oacc[mr][n], 0, 0, 0);
                    }
                }
            }
        }
    }

    // ---- 4-way end merge (single barrier in the kernel) ----
    if (wave >= 1) {
#pragma unroll
        for (int mr = 0; mr < 2; ++mr) {
            if (r == 0) {
#pragma unroll
                for (int g = 0; g < 4; ++g) {
                    mlbuf[wave - 1][mr * 16 + qd * 4 + g][0] = m2[mr][g];
                    mlbuf[wave - 1][mr * 16 + qd * 4 + g][1] = lr[mr][g];
                }
            }
#pragma unroll
            for (int n = 0; n < 8; ++n)
#pragma unroll
                for (int g = 0; g < 4; ++g)
                    obuf[wave - 1][(mr * 16 + qd * 4 + g) * 128 + n * 16 + r] = oacc[mr][n][g];
        }
    }
    __syncthreads();
    if (wave == 0) {
#pragma unroll
        for (int mr = 0; mr < 2; ++mr) {
            float a0[4], aw[3][4], inv[4];
#pragma unroll
            for (int g = 0; g < 4; ++g) {
                int row = mr * 16 + qd * 4 + g;
                float mn = m2[mr][g];
#pragma unroll
                for (int i = 0; i < 3; ++i) mn = fmaxf(mn, mlbuf[i][row][0]);
                a0[g] = __builtin_amdgcn_exp2f(m2[mr][g] - mn);
                float l = lr[mr][g] * a0[g];
#pragma unroll
                for (int i = 0; i < 3; ++i) {
                    aw[i][g] = __builtin_amdgcn_exp2f(mlbuf[i][row][0] - mn);
                    l += mlbuf[i][row][1] * aw[i][g];
                }
                inv[g] = 1.0f / (0.9f * l);
            }
#pragma unroll
            for (int n = 0; n < 8; ++n)
#pragma unroll
                for (int g = 0; g < 4; ++g) {
                    int row = mr * 16 + qd * 4 + g;
                    float o = oacc[mr][n][g] * a0[g];
#pragma unroll
                    for (int i = 0; i < 3; ++i)
                        o += obuf[i][row * 128 + n * 16 + r] * aw[i][g];
                    Og[(size_t)(blockRow0 + row) * HD + n * 16 + r] = o * inv[g];
                }
        }
    }
}

// ============================ fallback (round-3, verified) ============================
__global__ __launch_bounds__(256)
void fa_mfma(const float* __restrict__ Qg, const float* __restrict__ Kg,
             const float* __restrict__ Vg, float* __restrict__ Og) {
    __shared__ ushort khi[64 * KSTR];
    __shared__ ushort klo[64 * KSTR];
    __shared__ ushort vt[128 * VSTR];
    __shared__ ushort plsf[4][16 * PSTR];

    const int tid  = threadIdx.x;
    const int wave = tid >> 6;
    const int lane = tid & 63;
    const int r    = lane & 15;
    const int qd   = lane >> 4;
    const int blockRow0 = blockIdx.x * 64;
    const int b = blockRow0 >> 12;
    const int waveRow0 = blockRow0 + wave * 16;
    const size_t kvbase = (size_t)b * NV * HD;

    short8 qfh[4], qfl[4];
    {
        const float* qp = Qg + (size_t)(waveRow0 + r) * HD + qd * 8;
#pragma unroll
        for (int kc = 0; kc < 4; ++kc) {
            float x[8];
            *(float4*)&x[0] = *(const float4*)(qp + kc * 32);
            *(float4*)&x[4] = *(const float4*)(qp + kc * 32 + 4);
#pragma unroll
            for (int j = 0; j < 8; ++j) {
                ushort h = bf16rne(x[j]);
                qfh[kc][j] = (short)h;
                qfl[kc][j] = (short)bf16rne(x[j] - bf2f(h));
            }
        }
    }

    floatx4 oacc[8];
#pragma unroll
    for (int n = 0; n < 8; ++n) oacc[n] = (floatx4){0.f, 0.f, 0.f, 0.f};
    float m2[4] = {-INFINITY, -INFINITY, -INFINITY, -INFINITY};
    float lr[4] = {0.f, 0.f, 0.f, 0.f};

    for (int v0 = 0; v0 < NV; v0 += 64) {
        __syncthreads();
#pragma unroll
        for (int i = 0; i < 8; ++i) {
            int f = i * 256 + tid;
            int v = f >> 5;
            int h = (f & 31) * 4;
            float4 kv = *(const float4*)(Kg + kvbase + (size_t)(v0 + v) * HD + h);
            ushort4 hh, ll;
            hh.x = bf16rne(kv.x); ll.x = bf16rne(kv.x - bf2f(hh.x));
            hh.y = bf16rne(kv.y); ll.y = bf16rne(kv.y - bf2f(hh.y));
            hh.z = bf16rne(kv.z); ll.z = bf16rne(kv.z - bf2f(hh.z));
            hh.w = bf16rne(kv.w); ll.w = bf16rne(kv.w - bf2f(hh.w));
            *(ushort4*)&khi[v * KSTR + h] = hh;
            *(ushort4*)&klo[v * KSTR + h] = ll;
        }
        {
            int hp = tid & 63, rp = tid >> 6;
            int h = hp * 2;
            const float* vpb = Vg + kvbase + (size_t)v0 * HD + h;
#pragma unroll
            for (int i = 0; i < 8; ++i) {
                int v = i * 8 + rp * 2;
                float2 a = *(const float2*)(vpb + (size_t)v * HD);
                float2 c = *(const float2*)(vpb + (size_t)(v + 1) * HD);
                uint w0 = (uint)bf16rne(a.x) | ((uint)bf16rne(c.x) << 16);
                uint w1 = (uint)bf16rne(a.y) | ((uint)bf16rne(c.y) << 16);
                *(uint*)&vt[h * VSTR + v]       = w0;
                *(uint*)&vt[(h + 1) * VSTR + v] = w1;
            }
        }
        __syncthreads();

        floatx4 cf[4];
#pragma unroll
        for (int nb = 0; nb < 4; ++nb) cf[nb] = (floatx4){0.f, 0.f, 0.f, 0.f};
#pragma unroll
        for (int kc = 0; kc < 4; ++kc) {
#pragma unroll
            for (int nb = 0; nb < 4; ++nb) {
                int off = (nb * 16 + r) * KSTR + kc * 32 + qd * 8;
                short8 kh = *(const short8*)&khi[off];
                short8 kl = *(const short8*)&klo[off];
                cf[nb] = __builtin_amdgcn_mfma_f32_16x16x32_bf16(qfh[kc], kh, cf[nb], 0, 0, 0);
                cf[nb] = __builtin_amdgcn_mfma_f32_16x16x32_bf16(qfh[kc], kl, cf[nb], 0, 0, 0);
                cf[nb] = __builtin_amdgcn_mfma_f32_16x16x32_bf16(qfl[kc], kh, cf[nb], 0, 0, 0);
            }
        }

        float ts[4][4], p[4][4];
#pragma unroll
        for (int nb = 0; nb < 4; ++nb)
#pragma unroll
            for (int g = 0; g < 4; ++g) ts[nb][g] = cf[nb][g] * SCL2E;

        float tsum[4], alpha[4], lnew[4];
#pragma unroll
        for (int g = 0; g < 4; ++g) {
            float tmx = fmaxf(fmaxf(ts[0][g], ts[1][g]), fmaxf(ts[2][g], ts[3][g]));
#pragma unroll
            for (int off = 1; off < 16; off <<= 1)
                tmx = fmaxf(tmx, __shfl_xor(tmx, off));
            float mn = fmaxf(m2[g], tmx);
            alpha[g] = __builtin_amdgcn_exp2f(m2[g] - mn);
            m2[g] = mn;
        }
#pragma unroll
        for (int g = 0; g < 4; ++g) {
            float s = 0.f;
#pragma unroll
            for (int nb = 0; nb < 4; ++nb) {
                p[nb][g] = __builtin_amdgcn_exp2f(ts[nb][g] - m2[g]);
                s += p[nb][g];
            }
#pragma unroll
            for (int off = 1; off < 16; off <<= 1)
                s += __shfl_xor(s, off);
            tsum[g] = s;
            lnew[g] = lr[g] * alpha[g] + s;
            lr[g] = lnew[g];
        }

        bool rowneed = false;
#pragma unroll
        for (int g = 0; g < 4; ++g) rowneed |= (tsum[g] > 1e-8f * lnew[g]);

        if (__any(rowneed)) {
#pragma unroll
            for (int n = 0; n < 8; ++n)
#pragma unroll
                for (int g = 0; g < 4; ++g) oacc[n][g] *= alpha[g];

#pragma unroll
            for (int nb = 0; nb < 4; ++nb) {
                bool nbneed = false;
#pragma unroll
                for (int g = 0; g < 4; ++g) nbneed |= (p[nb][g] > 1e-8f * lnew[g]);
                if (__any(nbneed)) {
#pragma unroll
                    for (int g = 0; g < 4; ++g) {
                        uint j = (uint)(waveRow0 + qd * 4 + g) * (uint)NV
                               + (uint)(v0 + nb * 16 + r);
                        if (threefry_bits(j) >= KEEP_THRESH) p[nb][g] = 0.f;
                    }
                }
#pragma unroll
                for (int g = 0; g < 4; ++g)
                    plsf[wave][(qd * 4 + g) * PSTR + nb * 16 + r] = bf16rne(p[nb][g]);
            }
            __asm__ volatile("s_waitcnt lgkmcnt(0)" ::: "memory");

#pragma unroll
            for (int kc2 = 0; kc2 < 2; ++kc2) {
                short8 pa = *(const short8*)&plsf[wave][r * PSTR + kc2 * 32 + qd * 8];
#pragma unroll
                for (int n = 0; n < 8; ++n) {
                    int off = (n * 16 + r) * VSTR + kc2 * 32 + qd * 8;
                    ushort4 u0 = *(const ushort4*)&vt[off];
                    ushort4 u1 = *(const ushort4*)&vt[off + 4];
                    short8 vb;
                    vb[0] = (short)u0.x; vb[1] = (short)u0.y; vb[2] = (short)u0.z; vb[3] = (short)u0.w;
                    vb[4] = (short)u1.x; vb[5] = (short)u1.y; vb[6] = (short)u1.z; vb[7] = (short)u1.w;
                    oacc[n] = __builtin_amdgcn_mfma_f32_16x16x32_bf16(pa, vb, oacc[n], 0, 0, 0);
                }
            }
        }
    }

    float inv[4];
#pragma unroll
    for (int g = 0; g < 4; ++g) inv[g] = 1.0f / (0.9f * lr[g]);
#pragma unroll
    for (int n = 0; n < 8; ++n)
#pragma unroll
        for (int g = 0; g < 4; ++g)
            Og[(size_t)(waveRow0 + qd * 4 + g) * HD + n * 16 + r] = oacc[n][g] * inv[g];
}

extern "C" void kernel_launch(void* const* d_in, const int* in_sizes, int n_in,
                              void* d_out, int out_size, void* d_ws, size_t ws_size,
                              hipStream_t stream) {
    (void)in_sizes; (void)n_in; (void)out_size;
    const float* Qg = (const float*)d_in[0];
    const float* Kg = (const float*)d_in[1];
    const float* Vg = (const float*)d_in[2];
    float* Og = (float*)d_out;
    if (ws_size >= WS_NEEDED) {
        ushort* W = (ushort*)d_ws;
        prepass<<<dim3(512), 256, 0, stream>>>(Kg, Vg, W);
        fa_mfma7<<<dim3(NBATCH * NQ / 32), 256, 0, stream>>>(Qg, (const ushort*)W, Og);
    } else {
        fa_mfma<<<dim3(NBATCH * NQ / 64), 256, 0, stream>>>(Qg, Kg, Vg, Og);
    }
}